// Round 5
// baseline (421.941 us; speedup 1.0000x reference)
//
#include <hip/hip_runtime.h>
#include <hip/hip_bf16.h>
#include <cstddef>

#define NB_NODES 44800   // B*L
#define NDOCS 128
#define DLEN 350
#define DIM 768
#define HID 256
#define NCLS 20
#define NHEADS 8
#define ZROW 352         // transposed z row stride (nodes axis, f32)

typedef __bf16 v8bf __attribute__((ext_vector_type(8)));
typedef __bf16 v4bf __attribute__((ext_vector_type(4)));
typedef __bf16 v2bf __attribute__((ext_vector_type(2)));
typedef float v4f __attribute__((ext_vector_type(4)));
typedef float v2f __attribute__((ext_vector_type(2)));

// ---- W1 [768,256] f32 -> W1T [256,768] bf16 so B-fragments are contiguous 16B loads
__global__ __launch_bounds__(256) void k_transpose(const float* __restrict__ W1,
                                                   __bf16* __restrict__ W1T) {
  int idx = blockIdx.x * 256 + threadIdx.x;   // idx = n*768 + k
  int n = idx / 768, k = idx - n * 768;
  W1T[idx] = (__bf16)W1[k * 256 + n];
}

// ---- fused gather + GEMM1(relu) + GEMM2 -> h0 [N,20] f32
// BARRIER-FREE K-loop. r0-r4 all shared a barrier-per-K-tile skeleton and all landed
// 100-118us with every pipe <15% busy: the compiler's vmcnt(0) drain before each
// s_barrier re-exposes full gather latency 12x/block, and prefetch depth can't help
// (r4: 3-deep ring == 1-deep within noise). Fix: each wave loads its own A-fragments
// directly global->VGPR -- the MFMA A-frag layout (lane l: row l&15, k=(l>>4)*8+e)
// IS the gather pattern, so LDS staging bought nothing but the barrier. 4x intra-block
// A redundancy is absorbed by L1/L2 (4 waves read identical lines). LDS now epilogue-
// only (26.6 KB -> 5 blocks/CU); waves run unsynchronized until the 4-barrier epilogue.
__global__ __launch_bounds__(256) void k_mlp(
    const int* __restrict__ node_ids, const float* __restrict__ emb,
    const __bf16* __restrict__ W1T, const float* __restrict__ b1,
    const float* __restrict__ W2, const float* __restrict__ b2,
    float* __restrict__ h0) {
  __shared__ __align__(16) char smem[26880];
  float*  xs = (float*)smem;                  // [16][260] f32, 16640 B (epilogue)
  __bf16* w2s = (__bf16*)(smem + 16640);      // 10240 B
  int tid = threadIdx.x;
  int wave = tid >> 6, lane = tid & 63;
  int quad = lane >> 4, l16 = lane & 15;
  int m0 = blockIdx.x * 32;

  // W2 -> bf16 LDS up front (coalesced); consumed only in the epilogue.
  for (int i = tid; i < HID * NCLS; i += 256) w2s[i] = (__bf16)W2[i];

  // Per-lane A row pointers (identical across the 4 waves -- intentional redundancy).
  // Fragment ms: lane l holds row ms*16 + l16, k = ks*32 + quad*8 + e (e=0..7).
  const float* rp0 = emb + (size_t)node_ids[m0 + l16] * DIM + quad * 8;
  const float* rp1 = emb + (size_t)node_ids[m0 + 16 + l16] * DIM + quad * 8;

  v4f acc[2][4];
#pragma unroll
  for (int ms = 0; ms < 2; ++ms)
#pragma unroll
    for (int j = 0; j < 4; ++j) acc[ms][j] = (v4f){0.f, 0.f, 0.f, 0.f};

#pragma unroll 3
  for (int kc = 0; kc < 12; ++kc) {
    int kb = kc * 64;
#pragma unroll
    for (int ks = 0; ks < 2; ++ks) {
      int ko = kb + ks * 32;
      // A fragments: 4 independent v4f loads per ms (no LDS, no barrier)
      v4f a0l = *(const v4f*)(rp0 + ko);
      v4f a0h = *(const v4f*)(rp0 + ko + 4);
      v4f a1l = *(const v4f*)(rp1 + ko);
      v4f a1h = *(const v4f*)(rp1 + ko + 4);
      v8bf bv[4];
#pragma unroll
      for (int j = 0; j < 4; ++j)
        bv[j] = *(const v8bf*)(W1T + (size_t)(wave * 64 + j * 16 + l16) * DIM + ko + quad * 8);
      v8bf af0, af1;
#pragma unroll
      for (int e = 0; e < 4; ++e) {
        af0[e] = (__bf16)a0l[e]; af0[4 + e] = (__bf16)a0h[e];
        af1[e] = (__bf16)a1l[e]; af1[4 + e] = (__bf16)a1h[e];
      }
#pragma unroll
      for (int j = 0; j < 4; ++j)
        acc[0][j] = __builtin_amdgcn_mfma_f32_16x16x32_bf16(af0, bv[j], acc[0][j], 0, 0, 0);
#pragma unroll
      for (int j = 0; j < 4; ++j)
        acc[1][j] = __builtin_amdgcn_mfma_f32_16x16x32_bf16(af1, bv[j], acc[1][j], 0, 0, 0);
    }
  }

#pragma unroll
  for (int ms = 0; ms < 2; ++ms) {            // panel = rows ms*16 .. ms*16+15
    if (ms) __syncthreads();                  // prev panel gemm2 reads done
#pragma unroll
    for (int j = 0; j < 4; ++j) {
      int col = wave * 64 + j * 16 + l16;
      float bb = b1[col];
#pragma unroll
      for (int r = 0; r < 4; ++r) {
        int lr = quad * 4 + r;                // C/D: col=l16, row=quad*4+r
        float v = acc[ms][j][r] + bb;
        xs[lr * 260 + col] = v > 0.f ? v : 0.f;
      }
    }
    __syncthreads();                          // xs panel ready (also orders w2s fill)
    // GEMM2: [16 x 256] @ [256 x 20] + b2 ; 160 threads, 2 cols each
    if (tid < 160) {
      int m = tid / 10, c0 = (tid % 10) * 2;
      float s0 = b2[c0], s1 = b2[c0 + 1];
      for (int k = 0; k < HID; ++k) {
        float x = xs[m * 260 + k];
        v2bf w = *(const v2bf*)(w2s + k * NCLS + c0);
        s0 += x * (float)w[0]; s1 += x * (float)w[1];
      }
      v2f o; o[0] = s0; o[1] = s1;
      *(v2f*)(h0 + (size_t)(m0 + ms * 16 + m) * NCLS + c0) = o;
    }
  }
}

// ---- one GAT head-layer per block (1024 blocks): z=h@W, banded softmax, 3 hops, elu.
// zT is TRANSPOSED [20][352]: all hop/write accesses are lane-consecutive b32 ->
// conflict-free (old ZSTR=24 row-major was a 16-way conflict, 6.1M SQ_LDS_BANK_CONFLICT).
__global__ __launch_bounds__(384) void k_gat(
    const float* __restrict__ hin, const float* __restrict__ gatW,
    const float* __restrict__ a_src, const float* __restrict__ a_dst,
    int layer, float* __restrict__ zout) {
  __shared__ float zT[NCLS * ZROW];    // 28.16 KB
  __shared__ float asv[DLEN], adv[DLEN];
  int tid = threadIdx.x;
  int head = blockIdx.x & 7;
  int doc = blockIdx.x >> 3;
  const float* W  = gatW  + (size_t)(layer * NHEADS + head) * NCLS * NCLS;  // uniform -> s_loads
  const float* av = a_src + (layer * NHEADS + head) * NCLS;
  const float* dv = a_dst + (layer * NHEADS + head) * NCLS;
  int r = tid;
  bool act = r < DLEN;

  float z0[NCLS];
  if (act) {
    const float* hr = hin + ((size_t)doc * DLEN + r) * NCLS;
    float h[NCLS];
#pragma unroll
    for (int q = 0; q < 5; ++q) {
      v4f t = *(const v4f*)(hr + q * 4);
#pragma unroll
      for (int e = 0; e < 4; ++e) h[q * 4 + e] = t[e];
    }
    float zacc[NCLS];
#pragma unroll
    for (int d = 0; d < NCLS; ++d) zacc[d] = 0.f;
#pragma unroll
    for (int c = 0; c < NCLS; ++c) {
      float hc = h[c];
#pragma unroll
      for (int d = 0; d < NCLS; ++d) zacc[d] += hc * W[c * NCLS + d];
    }
    float sa = 0.f, sd = 0.f;
#pragma unroll
    for (int d = 0; d < NCLS; ++d) { sa += zacc[d] * av[d]; sd += zacc[d] * dv[d]; }
    asv[r] = sa; adv[r] = sd;
#pragma unroll
    for (int c = 0; c < NCLS; ++c) zT[c * ZROW + r] = zacc[c];   // lane-consecutive
#pragma unroll
    for (int d = 0; d < NCLS; ++d) z0[d] = zacc[d];
  }
  __syncthreads();   // zT/asv/adv ready

  float att[7];
  if (act) {
    float ad = adv[r];
    float e[7]; float m = -1e30f;
#pragma unroll
    for (int j = 0; j < 7; ++j) {
      int s = r - 3 + j;
      bool valid = (s >= 0) && (s < DLEN);
      float x = valid ? asv[s] + ad : -1e30f;
      x = x > 0.f ? x : 0.2f * x;              // leaky_relu 0.2
      e[j] = valid ? x : -1e30f;
      if (e[j] > m) m = e[j];
    }
    float sum = 0.f;
#pragma unroll
    for (int j = 0; j < 7; ++j) {
      float ex = (e[j] > -1e29f) ? expf(e[j] - m) : 0.f;
      e[j] = ex; sum += ex;
    }
    float inv = 1.f / (sum + 1e-9f);
#pragma unroll
    for (int j = 0; j < 7; ++j) att[j] = e[j] * inv;
  }

  float vn[NCLS];
  for (int hop = 0; hop < 3; ++hop) {
    if (act) {
      float agg[NCLS];
#pragma unroll
      for (int c = 0; c < NCLS; ++c) agg[c] = 0.f;
#pragma unroll
      for (int j = 0; j < 7; ++j) {
        int s = r - 3 + j;
        s = s < 0 ? 0 : (s > DLEN - 1 ? DLEN - 1 : s);  // invalid slots have att 0
        float a = att[j];
#pragma unroll
        for (int c = 0; c < NCLS; ++c) agg[c] += a * zT[c * ZROW + s];  // lane-consecutive
      }
#pragma unroll
      for (int c = 0; c < NCLS; ++c) vn[c] = 0.85f * agg[c] + 0.15f * z0[c];
    }
    if (hop < 2) {
      __syncthreads();   // all reads of zT done
      if (act) {
#pragma unroll
        for (int c = 0; c < NCLS; ++c) zT[c * ZROW + r] = vn[c];
      }
      __syncthreads();   // zT updated
    }
  }

  if (act) {
    float* og = zout + ((size_t)head * NB_NODES + (size_t)doc * DLEN + r) * NCLS;
#pragma unroll
    for (int q = 0; q < 5; ++q) {
      v4f t;
#pragma unroll
      for (int e = 0; e < 4; ++e) {
        float x = vn[q * 4 + e];
        t[e] = x > 0.f ? x : expf(x) - 1.f;    // elu
      }
      *(v4f*)(og + q * 4) = t;
    }
  }
}

// ---- mean over heads, float4 (between layer 0 and layer 1)
__global__ __launch_bounds__(256) void k_headmean(
    const float* __restrict__ eluzt, float* __restrict__ hout) {
  int idx = blockIdx.x * 256 + threadIdx.x;   // < N*20/4 = 224000
  v4f s = (v4f){0.f, 0.f, 0.f, 0.f};
#pragma unroll
  for (int h = 0; h < NHEADS; ++h)
    s += ((const v4f*)eluzt)[(size_t)h * (NB_NODES * NCLS / 4) + idx];
  v4f o; o[0] = s[0] * 0.125f; o[1] = s[1] * 0.125f; o[2] = s[2] * 0.125f; o[3] = s[3] * 0.125f;
  ((v4f*)hout)[idx] = o;
}

// ---- fused head-mean + gated pool for layer 1: one block per doc
__global__ __launch_bounds__(384) void k_hm_pool(
    const float* __restrict__ eluzt, const float* __restrict__ w_gate,
    const float* __restrict__ b_gate, float* __restrict__ out) {
  __shared__ float red[6][NCLS];
  int tid = threadIdx.x;
  int doc = blockIdx.x;
  int r = tid;
  bool act = r < DLEN;

  float wg[NCLS];
#pragma unroll
  for (int c = 0; c < NCLS; ++c) wg[c] = w_gate[c];
  float contrib[NCLS];
#pragma unroll
  for (int c = 0; c < NCLS; ++c) contrib[c] = 0.f;
  if (act) {
    float hm[NCLS];
#pragma unroll
    for (int c = 0; c < NCLS; ++c) hm[c] = 0.f;
#pragma unroll
    for (int hd = 0; hd < NHEADS; ++hd) {
      const float* p = eluzt + ((size_t)hd * NB_NODES + (size_t)doc * DLEN + r) * NCLS;
#pragma unroll
      for (int q = 0; q < 5; ++q) {
        v4f t = *(const v4f*)(p + q * 4);
#pragma unroll
        for (int e = 0; e < 4; ++e) hm[q * 4 + e] += t[e];
      }
    }
    float d = b_gate[0];
#pragma unroll
    for (int c = 0; c < NCLS; ++c) { hm[c] *= 0.125f; d += hm[c] * wg[c]; }
    float g = 1.f / (1.f + expf(-d));
#pragma unroll
    for (int c = 0; c < NCLS; ++c) contrib[c] = g * hm[c];
  }
#pragma unroll
  for (int off = 32; off > 0; off >>= 1)
#pragma unroll
    for (int c = 0; c < NCLS; ++c) contrib[c] += __shfl_down(contrib[c], off);
  int wave = tid >> 6, lane = tid & 63;
  if (lane == 0)
#pragma unroll
    for (int c = 0; c < NCLS; ++c) red[wave][c] = contrib[c];
  __syncthreads();
  if (tid < NCLS) {
    float s = 0.f;
#pragma unroll
    for (int w = 0; w < 6; ++w) s += red[w][tid];
    out[doc * NCLS + tid] = s;
  }
}

extern "C" void kernel_launch(void* const* d_in, const int* in_sizes, int n_in,
                              void* d_out, int out_size, void* d_ws, size_t ws_size,
                              hipStream_t stream) {
  const int* node_ids = (const int*)d_in[0];
  // d_in[1..3] (edge_src/edge_dst/graph_id) unused: band structure is static
  const float* emb    = (const float*)d_in[4];
  const float* W1     = (const float*)d_in[5];
  const float* b1     = (const float*)d_in[6];
  const float* W2     = (const float*)d_in[7];
  const float* b2     = (const float*)d_in[8];
  const float* gatW   = (const float*)d_in[9];
  const float* a_src  = (const float*)d_in[10];
  const float* a_dst  = (const float*)d_in[11];
  const float* w_gate = (const float*)d_in[12];
  const float* b_gate = (const float*)d_in[13];
  float* out = (float*)d_out;
  char* ws = (char*)d_ws;

  __bf16* W1T = (__bf16*)(ws + 0);        //   393,216 B
  float* hA  = (float*)(ws + 393216);     // 3,584,000 B
  float* hB  = (float*)(ws + 3977216);    // 3,584,000 B
  float* zt  = (float*)(ws + 7561216);    // 28,672,000 B (total ~36.2 MB)

  k_transpose<<<768, 256, 0, stream>>>(W1, W1T);
  k_mlp<<<NB_NODES / 32, 256, 0, stream>>>(node_ids, emb, W1T, b1, W2, b2, hA);
  // layer 0
  k_gat<<<NDOCS * NHEADS, 384, 0, stream>>>(hA, gatW, a_src, a_dst, 0, zt);
  k_headmean<<<(NB_NODES * NCLS / 4) / 256, 256, 0, stream>>>(zt, hB);
  // layer 1
  k_gat<<<NDOCS * NHEADS, 384, 0, stream>>>(hB, gatW, a_src, a_dst, 1, zt);
  k_hm_pool<<<NDOCS, 384, 0, stream>>>(zt, w_gate, b_gate, out);
}

// Round 6
// 351.048 us; speedup vs baseline: 1.2019x; 1.2019x over previous
//
#include <hip/hip_runtime.h>
#include <hip/hip_bf16.h>
#include <cstddef>

#define NB_NODES 44800   // B*L
#define NDOCS 128
#define DLEN 350
#define DIM 768
#define HID 256
#define NCLS 20
#define NHEADS 8
#define ZROW 352         // transposed z row stride (nodes axis, f32)
#define ASTR 800         // A LDS row stride (bf16): 1600 B -> b128 frag reads hit all
                         // 8 bank-quads with distinct 16B slots = optimal (no conflict)

typedef __bf16 v8bf __attribute__((ext_vector_type(8)));
typedef __bf16 v4bf __attribute__((ext_vector_type(4)));
typedef __bf16 v2bf __attribute__((ext_vector_type(2)));
typedef float v4f __attribute__((ext_vector_type(4)));
typedef float v2f __attribute__((ext_vector_type(2)));

// ---- W1 [768,256] f32 -> W1P fragment-packed bf16: lane l of wave reading
// (col-block cb, k-step ks) loads ONE contiguous v8bf at (cb*24+ks)*512 + l*8,
// holding W1[k = ks*32 + (l>>4)*8 + e][col = cb*16 + (l&15)].
__global__ __launch_bounds__(256) void k_pack(const float* __restrict__ W1,
                                              __bf16* __restrict__ W1P) {
  int idx = blockIdx.x * 256 + threadIdx.x;   // < 16*24*512 = 196608
  int e = idx & 7;
  int l = (idx >> 3) & 63;
  int rest = idx >> 9;                        // cb*24 + ks
  int ks = rest % 24;
  int cb = rest / 24;
  int k = ks * 32 + (l >> 4) * 8 + e;
  int col = cb * 16 + (l & 15);
  W1P[idx] = (__bf16)W1[k * 256 + col];
}

// ---- fused gather + GEMM1(relu) + GEMM2 -> h0 [N,20] f32
// ACCESS-PATTERN fix (r0-r5 all ~100-160us with every pipe <20% busy at a fixed
// ~68MB FETCH => HBM random-256B-granule cap ~700GB/s was the invariant):
// each emb row is now fetched ONCE as a contiguous 3KB burst (3x 1KB coalesced
// wave-loads), cvt'd to bf16 into a full-K LDS panel [32][ASTR]. ONE barrier after
// staging; the K-loop is barrier-free and reads A only from LDS, B as contiguous
// 1KB loads from fragment-packed W1P (L2-resident). LDS 51.2KB -> 3 blocks/CU;
// epilogue reuses the A region. NO min-waves bound (r2: forcing it spilled 200MB).
__global__ __launch_bounds__(256) void k_mlp(
    const int* __restrict__ node_ids, const float* __restrict__ emb,
    const __bf16* __restrict__ W1P, const float* __restrict__ b1,
    const float* __restrict__ W2, const float* __restrict__ b2,
    float* __restrict__ h0) {
  __shared__ __align__(16) char smem[51200];
  __bf16* Asl = (__bf16*)smem;                // [32][ASTR] bf16 (51.2 KB)
  float*  xs  = (float*)smem;                 // epilogue: [16][260] f32 (16.64 KB)
  __bf16* w2s = (__bf16*)(smem + 16640);      // epilogue: 10.24 KB
  int tid = threadIdx.x;
  int wave = tid >> 6, lane = tid & 63;
  int quad = lane >> 4, l16 = lane & 15;
  int m0 = blockIdx.x * 32;

  // ---- stage A: wave w owns rows w*8..w*8+7; per row 3x contiguous 1KB loads.
  {
    int r0 = wave * 8;
    int nid[8];
#pragma unroll
    for (int rr = 0; rr < 8; ++rr) nid[rr] = node_ids[m0 + r0 + rr];  // wave-uniform
#pragma unroll
    for (int p = 0; p < 3; ++p) {
      v4f t[8];
#pragma unroll
      for (int rr = 0; rr < 8; ++rr)
        t[rr] = *(const v4f*)(emb + (size_t)nid[rr] * DIM + p * 256 + lane * 4);
#pragma unroll
      for (int rr = 0; rr < 8; ++rr) {
        v4bf b;
#pragma unroll
        for (int e = 0; e < 4; ++e) b[e] = (__bf16)t[rr][e];
        // ds_write_b64, bank = const + 2*lane -> 2-way (free)
        *(v4bf*)(Asl + (r0 + rr) * ASTR + p * 256 + lane * 4) = b;
      }
    }
  }

  v4f acc[2][4];
#pragma unroll
  for (int ms = 0; ms < 2; ++ms)
#pragma unroll
    for (int j = 0; j < 4; ++j) acc[ms][j] = (v4f){0.f, 0.f, 0.f, 0.f};

  __syncthreads();   // A panel ready; the ONLY barrier before the epilogue

  // ---- barrier-free K-loop: A from LDS, B contiguous from W1P.
  const __bf16* wpB = W1P + (size_t)wave * 49152 + lane * 8;   // + j*12288 + ks*512
#pragma unroll 4
  for (int ks = 0; ks < 24; ++ks) {
    v8bf a0 = *(const v8bf*)(Asl + l16 * ASTR + ks * 32 + quad * 8);
    v8bf a1 = *(const v8bf*)(Asl + (16 + l16) * ASTR + ks * 32 + quad * 8);
    v8bf bv[4];
#pragma unroll
    for (int j = 0; j < 4; ++j)
      bv[j] = *(const v8bf*)(wpB + j * 12288 + ks * 512);
#pragma unroll
    for (int j = 0; j < 4; ++j) {
      acc[0][j] = __builtin_amdgcn_mfma_f32_16x16x32_bf16(a0, bv[j], acc[0][j], 0, 0, 0);
      acc[1][j] = __builtin_amdgcn_mfma_f32_16x16x32_bf16(a1, bv[j], acc[1][j], 0, 0, 0);
    }
  }

  __syncthreads();   // all waves done reading Asl; reuse region as xs/w2s
  for (int i = tid; i < HID * NCLS; i += 256) w2s[i] = (__bf16)W2[i];

#pragma unroll
  for (int ms = 0; ms < 2; ++ms) {            // panel = rows ms*16 .. ms*16+15
    if (ms) __syncthreads();                  // prev panel gemm2 reads done
#pragma unroll
    for (int j = 0; j < 4; ++j) {
      int col = wave * 64 + j * 16 + l16;
      float bb = b1[col];
#pragma unroll
      for (int r = 0; r < 4; ++r) {
        int lr = quad * 4 + r;                // C/D: col=l16, row=quad*4+r
        float v = acc[ms][j][r] + bb;
        xs[lr * 260 + col] = v > 0.f ? v : 0.f;
      }
    }
    __syncthreads();                          // xs panel (and w2s fill) visible
    // GEMM2: [16 x 256] @ [256 x 20] + b2 ; 160 threads, 2 cols each
    if (tid < 160) {
      int m = tid / 10, c0 = (tid % 10) * 2;
      float s0 = b2[c0], s1 = b2[c0 + 1];
      for (int k = 0; k < HID; ++k) {
        float x = xs[m * 260 + k];
        v2bf w = *(const v2bf*)(w2s + k * NCLS + c0);
        s0 += x * (float)w[0]; s1 += x * (float)w[1];
      }
      v2f o; o[0] = s0; o[1] = s1;
      *(v2f*)(h0 + (size_t)(m0 + ms * 16 + m) * NCLS + c0) = o;
    }
  }
}

// ---- one GAT head-layer per block (1024 blocks): z=h@W, banded softmax, 3 hops, elu.
// zT is TRANSPOSED [20][352]: all hop/write accesses are lane-consecutive b32 ->
// conflict-free (old ZSTR=24 row-major was a 16-way conflict, 6.1M SQ_LDS_BANK_CONFLICT).
__global__ __launch_bounds__(384) void k_gat(
    const float* __restrict__ hin, const float* __restrict__ gatW,
    const float* __restrict__ a_src, const float* __restrict__ a_dst,
    int layer, float* __restrict__ zout) {
  __shared__ float zT[NCLS * ZROW];    // 28.16 KB
  __shared__ float asv[DLEN], adv[DLEN];
  int tid = threadIdx.x;
  int head = blockIdx.x & 7;
  int doc = blockIdx.x >> 3;
  const float* W  = gatW  + (size_t)(layer * NHEADS + head) * NCLS * NCLS;  // uniform -> s_loads
  const float* av = a_src + (layer * NHEADS + head) * NCLS;
  const float* dv = a_dst + (layer * NHEADS + head) * NCLS;
  int r = tid;
  bool act = r < DLEN;

  float z0[NCLS];
  if (act) {
    const float* hr = hin + ((size_t)doc * DLEN + r) * NCLS;
    float h[NCLS];
#pragma unroll
    for (int q = 0; q < 5; ++q) {
      v4f t = *(const v4f*)(hr + q * 4);
#pragma unroll
      for (int e = 0; e < 4; ++e) h[q * 4 + e] = t[e];
    }
    float zacc[NCLS];
#pragma unroll
    for (int d = 0; d < NCLS; ++d) zacc[d] = 0.f;
#pragma unroll
    for (int c = 0; c < NCLS; ++c) {
      float hc = h[c];
#pragma unroll
      for (int d = 0; d < NCLS; ++d) zacc[d] += hc * W[c * NCLS + d];
    }
    float sa = 0.f, sd = 0.f;
#pragma unroll
    for (int d = 0; d < NCLS; ++d) { sa += zacc[d] * av[d]; sd += zacc[d] * dv[d]; }
    asv[r] = sa; adv[r] = sd;
#pragma unroll
    for (int c = 0; c < NCLS; ++c) zT[c * ZROW + r] = zacc[c];   // lane-consecutive
#pragma unroll
    for (int d = 0; d < NCLS; ++d) z0[d] = zacc[d];
  }
  __syncthreads();   // zT/asv/adv ready

  float att[7];
  if (act) {
    float ad = adv[r];
    float e[7]; float m = -1e30f;
#pragma unroll
    for (int j = 0; j < 7; ++j) {
      int s = r - 3 + j;
      bool valid = (s >= 0) && (s < DLEN);
      float x = valid ? asv[s] + ad : -1e30f;
      x = x > 0.f ? x : 0.2f * x;              // leaky_relu 0.2
      e[j] = valid ? x : -1e30f;
      if (e[j] > m) m = e[j];
    }
    float sum = 0.f;
#pragma unroll
    for (int j = 0; j < 7; ++j) {
      float ex = (e[j] > -1e29f) ? expf(e[j] - m) : 0.f;
      e[j] = ex; sum += ex;
    }
    float inv = 1.f / (sum + 1e-9f);
#pragma unroll
    for (int j = 0; j < 7; ++j) att[j] = e[j] * inv;
  }

  float vn[NCLS];
  for (int hop = 0; hop < 3; ++hop) {
    if (act) {
      float agg[NCLS];
#pragma unroll
      for (int c = 0; c < NCLS; ++c) agg[c] = 0.f;
#pragma unroll
      for (int j = 0; j < 7; ++j) {
        int s = r - 3 + j;
        s = s < 0 ? 0 : (s > DLEN - 1 ? DLEN - 1 : s);  // invalid slots have att 0
        float a = att[j];
#pragma unroll
        for (int c = 0; c < NCLS; ++c) agg[c] += a * zT[c * ZROW + s];  // lane-consecutive
      }
#pragma unroll
      for (int c = 0; c < NCLS; ++c) vn[c] = 0.85f * agg[c] + 0.15f * z0[c];
    }
    if (hop < 2) {
      __syncthreads();   // all reads of zT done
      if (act) {
#pragma unroll
        for (int c = 0; c < NCLS; ++c) zT[c * ZROW + r] = vn[c];
      }
      __syncthreads();   // zT updated
    }
  }

  if (act) {
    float* og = zout + ((size_t)head * NB_NODES + (size_t)doc * DLEN + r) * NCLS;
#pragma unroll
    for (int q = 0; q < 5; ++q) {
      v4f t;
#pragma unroll
      for (int e = 0; e < 4; ++e) {
        float x = vn[q * 4 + e];
        t[e] = x > 0.f ? x : expf(x) - 1.f;    // elu
      }
      *(v4f*)(og + q * 4) = t;
    }
  }
}

// ---- mean over heads, float4 (between layer 0 and layer 1)
__global__ __launch_bounds__(256) void k_headmean(
    const float* __restrict__ eluzt, float* __restrict__ hout) {
  int idx = blockIdx.x * 256 + threadIdx.x;   // < N*20/4 = 224000
  v4f s = (v4f){0.f, 0.f, 0.f, 0.f};
#pragma unroll
  for (int h = 0; h < NHEADS; ++h)
    s += ((const v4f*)eluzt)[(size_t)h * (NB_NODES * NCLS / 4) + idx];
  v4f o; o[0] = s[0] * 0.125f; o[1] = s[1] * 0.125f; o[2] = s[2] * 0.125f; o[3] = s[3] * 0.125f;
  ((v4f*)hout)[idx] = o;
}

// ---- fused head-mean + gated pool for layer 1: one block per doc
__global__ __launch_bounds__(384) void k_hm_pool(
    const float* __restrict__ eluzt, const float* __restrict__ w_gate,
    const float* __restrict__ b_gate, float* __restrict__ out) {
  __shared__ float red[6][NCLS];
  int tid = threadIdx.x;
  int doc = blockIdx.x;
  int r = tid;
  bool act = r < DLEN;

  float wg[NCLS];
#pragma unroll
  for (int c = 0; c < NCLS; ++c) wg[c] = w_gate[c];
  float contrib[NCLS];
#pragma unroll
  for (int c = 0; c < NCLS; ++c) contrib[c] = 0.f;
  if (act) {
    float hm[NCLS];
#pragma unroll
    for (int c = 0; c < NCLS; ++c) hm[c] = 0.f;
#pragma unroll
    for (int hd = 0; hd < NHEADS; ++hd) {
      const float* p = eluzt + ((size_t)hd * NB_NODES + (size_t)doc * DLEN + r) * NCLS;
#pragma unroll
      for (int q = 0; q < 5; ++q) {
        v4f t = *(const v4f*)(p + q * 4);
#pragma unroll
        for (int e = 0; e < 4; ++e) hm[q * 4 + e] += t[e];
      }
    }
    float d = b_gate[0];
#pragma unroll
    for (int c = 0; c < NCLS; ++c) { hm[c] *= 0.125f; d += hm[c] * wg[c]; }
    float g = 1.f / (1.f + expf(-d));
#pragma unroll
    for (int c = 0; c < NCLS; ++c) contrib[c] = g * hm[c];
  }
#pragma unroll
  for (int off = 32; off > 0; off >>= 1)
#pragma unroll
    for (int c = 0; c < NCLS; ++c) contrib[c] += __shfl_down(contrib[c], off);
  int wave = tid >> 6, lane = tid & 63;
  if (lane == 0)
#pragma unroll
    for (int c = 0; c < NCLS; ++c) red[wave][c] = contrib[c];
  __syncthreads();
  if (tid < NCLS) {
    float s = 0.f;
#pragma unroll
    for (int w = 0; w < 6; ++w) s += red[w][tid];
    out[doc * NCLS + tid] = s;
  }
}

extern "C" void kernel_launch(void* const* d_in, const int* in_sizes, int n_in,
                              void* d_out, int out_size, void* d_ws, size_t ws_size,
                              hipStream_t stream) {
  const int* node_ids = (const int*)d_in[0];
  // d_in[1..3] (edge_src/edge_dst/graph_id) unused: band structure is static
  const float* emb    = (const float*)d_in[4];
  const float* W1     = (const float*)d_in[5];
  const float* b1     = (const float*)d_in[6];
  const float* W2     = (const float*)d_in[7];
  const float* b2     = (const float*)d_in[8];
  const float* gatW   = (const float*)d_in[9];
  const float* a_src  = (const float*)d_in[10];
  const float* a_dst  = (const float*)d_in[11];
  const float* w_gate = (const float*)d_in[12];
  const float* b_gate = (const float*)d_in[13];
  float* out = (float*)d_out;
  char* ws = (char*)d_ws;

  __bf16* W1P = (__bf16*)(ws + 0);        //   393,216 B
  float* hA  = (float*)(ws + 393216);     // 3,584,000 B
  float* hB  = (float*)(ws + 3977216);    // 3,584,000 B
  float* zt  = (float*)(ws + 7561216);    // 28,672,000 B (total ~36.2 MB)

  k_pack<<<768, 256, 0, stream>>>(W1, W1P);
  k_mlp<<<NB_NODES / 32, 256, 0, stream>>>(node_ids, emb, W1P, b1, W2, b2, hA);
  // layer 0
  k_gat<<<NDOCS * NHEADS, 384, 0, stream>>>(hA, gatW, a_src, a_dst, 0, zt);
  k_headmean<<<(NB_NODES * NCLS / 4) / 256, 256, 0, stream>>>(zt, hB);
  // layer 1
  k_gat<<<NDOCS * NHEADS, 384, 0, stream>>>(hB, gatW, a_src, a_dst, 1, zt);
  k_hm_pool<<<NDOCS, 384, 0, stream>>>(zt, w_gate, b_gate, out);
}